// Round 1
// baseline (299.410 us; speedup 1.0000x reference)
//
#include <hip/hip_runtime.h>

#define B_N 131072
#define IN_N 40
#define P_N 128
#define H_N 256

typedef __bf16 bf16x8 __attribute__((ext_vector_type(8)));
typedef float f32x4 __attribute__((ext_vector_type(4)));

#define MFMA(a, b, c) __builtin_amdgcn_mfma_f32_16x16x32_bf16(a, b, c, 0, 0, 0)

__device__ __forceinline__ unsigned short f2bf(float f) {
  union { float f; unsigned u; } a; a.f = f;
  unsigned u = a.u;
  u += 0x7FFFu + ((u >> 16) & 1u);   // RNE
  return (unsigned short)(u >> 16);
}
__device__ __forceinline__ float bf2f(unsigned short h) {
  union { unsigned u; float f; } a; a.u = ((unsigned)h) << 16;
  return a.f;
}

// ws layout (ushort elements):
//   [0, 8192)            W_proj padded to [128][64] (cols 40..63 zero)
//   [8192, 106496)       W_ih  [768][128]
//   [106496, 303104)     W_hh  [768][256]
#define WS_WP 0
#define WS_WIH 8192
#define WS_WHH (8192 + 98304)
#define WS_TOT (8192 + 98304 + 196608)

__global__ void cvt_w(const float* __restrict__ Wp, const float* __restrict__ Wih,
                      const float* __restrict__ Whh, unsigned short* __restrict__ ws) {
  int i = blockIdx.x * 256 + threadIdx.x;
  if (i < 8192) {
    int r = i >> 6, c = i & 63;
    ws[i] = f2bf(c < IN_N ? Wp[r * IN_N + c] : 0.f);
  } else if (i < WS_WHH) {
    ws[i] = f2bf(Wih[i - WS_WIH]);
  } else if (i < WS_TOT) {
    ws[i] = f2bf(Whh[i - WS_WHH]);
  }
}

// Block: 512 threads = 8 waves, 64 batch rows. Wave w owns 32 H-columns (full 64 rows).
__global__ __launch_bounds__(512, 2) void gru_fused(
    const float* __restrict__ x, const float* __restrict__ h0,
    const unsigned short* __restrict__ ws,
    const float* __restrict__ bp, const float* __restrict__ bih,
    const float* __restrict__ bhh, const float* __restrict__ Whead,
    const float* __restrict__ bhead, float* __restrict__ out) {
  // +8 ushort pad per row: stride%32banks == +4 banks/row -> 2-way (free), keeps 16B align
  __shared__ unsigned short xs[64][72];    // x tile, K padded to 64
  __shared__ unsigned short hs[64][264];   // h tile, K=256
  __shared__ unsigned short xp[64][136];   // x_proj tile, K=128
  __shared__ float predp[8][64];

  const int tid = threadIdx.x;
  const int b0 = blockIdx.x * 64;
  const int lane = tid & 63;
  const int w = tid >> 6;       // wave 0..7
  const int l15 = lane & 15;
  const int l4 = lane >> 4;     // 0..3

  // ---------------- phase 0: stage x (bf16, zero-pad K) and h (bf16) ----------------
  for (int i = tid; i < 64 * 64; i += 512) {
    int r = i >> 6, c = i & 63;
    xs[r][c] = f2bf(c < IN_N ? x[(size_t)(b0 + r) * IN_N + c] : 0.f);
  }
  for (int i = tid; i < 64 * 64; i += 512) {  // 4096 float4 = 64 rows * 64 float4/row
    int r = i >> 6, c4 = (i & 63) * 4;
    float4 v = *reinterpret_cast<const float4*>(&h0[(size_t)(b0 + r) * H_N + c4]);
    ushort4 u;
    u.x = f2bf(v.x); u.y = f2bf(v.y); u.z = f2bf(v.z); u.w = f2bf(v.w);
    *reinterpret_cast<ushort4*>(&hs[r][c4]) = u;
  }
  __syncthreads();

  // ---------------- phase 1: x_proj = x @ Wp^T + bp -> xp (bf16) ----------------
  {
    const int col = w * 16 + l15;   // P column, wave owns 16 cols
    const int koff = l4 * 8;
    f32x4 acc[4] = {};
#pragma unroll
    for (int ks = 0; ks < 2; ++ks) {
      const int k = ks * 32 + koff;
      const bf16x8 bf = *reinterpret_cast<const bf16x8*>(&ws[WS_WP + col * 64 + k]);
#pragma unroll
      for (int mi = 0; mi < 4; ++mi) {
        const bf16x8 af = *reinterpret_cast<const bf16x8*>(&xs[mi * 16 + l15][k]);
        acc[mi] = MFMA(af, bf, acc[mi]);
      }
    }
    const float bias = bp[col];
#pragma unroll
    for (int mi = 0; mi < 4; ++mi)
#pragma unroll
      for (int r = 0; r < 4; ++r)
        xp[mi * 16 + l4 * 4 + r][col] = f2bf(acc[mi][r] + bias);
  }
  __syncthreads();

  // ---------------- phase 2: gates + epilogue ----------------
  {
    const int cb = w * 32;          // this wave's H-column base
    const int koff = l4 * 8;
    f32x4 aR[4][2], aZ[4][2], aIN[4][2], aHN[4][2];
#pragma unroll
    for (int ni = 0; ni < 2; ++ni) {
      const int col = cb + ni * 16 + l15;
      const float vR = bih[col] + bhh[col];
      const float vZ = bih[H_N + col] + bhh[H_N + col];
      const float vIN = bih[2 * H_N + col];
      const float vHN = bhh[2 * H_N + col];
#pragma unroll
      for (int mi = 0; mi < 4; ++mi) {
        aR[mi][ni] = (f32x4){vR, vR, vR, vR};
        aZ[mi][ni] = (f32x4){vZ, vZ, vZ, vZ};
        aIN[mi][ni] = (f32x4){vIN, vIN, vIN, vIN};
        aHN[mi][ni] = (f32x4){vHN, vHN, vHN, vHN};
      }
    }
    // gi contributions: K=128 over xp
#pragma unroll
    for (int ks = 0; ks < 4; ++ks) {
      const int k = ks * 32 + koff;
      bf16x8 a[4];
#pragma unroll
      for (int mi = 0; mi < 4; ++mi)
        a[mi] = *reinterpret_cast<const bf16x8*>(&xp[mi * 16 + l15][k]);
#pragma unroll
      for (int ni = 0; ni < 2; ++ni) {
        const unsigned short* wr = &ws[WS_WIH + (cb + ni * 16 + l15) * 128 + k];
        const bf16x8 br = *reinterpret_cast<const bf16x8*>(wr);
        const bf16x8 bz = *reinterpret_cast<const bf16x8*>(wr + 256 * 128);
        const bf16x8 bn = *reinterpret_cast<const bf16x8*>(wr + 512 * 128);
#pragma unroll
        for (int mi = 0; mi < 4; ++mi) {
          aR[mi][ni] = MFMA(a[mi], br, aR[mi][ni]);
          aZ[mi][ni] = MFMA(a[mi], bz, aZ[mi][ni]);
          aIN[mi][ni] = MFMA(a[mi], bn, aIN[mi][ni]);
        }
      }
    }
    // gh contributions: K=256 over hs
#pragma unroll
    for (int ks = 0; ks < 8; ++ks) {
      const int k = ks * 32 + koff;
      bf16x8 a[4];
#pragma unroll
      for (int mi = 0; mi < 4; ++mi)
        a[mi] = *reinterpret_cast<const bf16x8*>(&hs[mi * 16 + l15][k]);
#pragma unroll
      for (int ni = 0; ni < 2; ++ni) {
        const unsigned short* wr = &ws[WS_WHH + (cb + ni * 16 + l15) * 256 + k];
        const bf16x8 br = *reinterpret_cast<const bf16x8*>(wr);
        const bf16x8 bz = *reinterpret_cast<const bf16x8*>(wr + 256 * 256);
        const bf16x8 bn = *reinterpret_cast<const bf16x8*>(wr + 512 * 256);
#pragma unroll
        for (int mi = 0; mi < 4; ++mi) {
          aR[mi][ni] = MFMA(a[mi], br, aR[mi][ni]);
          aZ[mi][ni] = MFMA(a[mi], bz, aZ[mi][ni]);
          aHN[mi][ni] = MFMA(a[mi], bn, aHN[mi][ni]);
        }
      }
    }
    // epilogue: gate math in f32, store h_new, accumulate pred partials
    float ps[4][4] = {};
#pragma unroll
    for (int mi = 0; mi < 4; ++mi) {
#pragma unroll
      for (int ni = 0; ni < 2; ++ni) {
        const int col = cb + ni * 16 + l15;
        const float wh = Whead[col];
#pragma unroll
        for (int r = 0; r < 4; ++r) {
          const int row = mi * 16 + l4 * 4 + r;
          const float rg = 1.f / (1.f + __expf(-aR[mi][ni][r]));
          const float zg = 1.f / (1.f + __expf(-aZ[mi][ni][r]));
          const float ng = tanhf(aIN[mi][ni][r] + rg * aHN[mi][ni][r]);
          const float hv = bf2f(hs[row][col]);
          const float hn = (1.f - zg) * ng + zg * hv;
          out[(size_t)B_N + (size_t)(b0 + row) * H_N + col] = hn;
          ps[mi][r] += hn * wh;
        }
      }
    }
#pragma unroll
    for (int mi = 0; mi < 4; ++mi)
#pragma unroll
      for (int r = 0; r < 4; ++r) {
        float s = ps[mi][r];
        s += __shfl_xor(s, 1);
        s += __shfl_xor(s, 2);
        s += __shfl_xor(s, 4);
        s += __shfl_xor(s, 8);
        if (l15 == 0) predp[w][mi * 16 + l4 * 4 + r] = s;
      }
  }
  __syncthreads();

  // ---------------- pred: cross-wave combine, coalesced store ----------------
  if (tid < 64) {
    float s = bhead[0];
#pragma unroll
    for (int w2 = 0; w2 < 8; ++w2) s += predp[w2][tid];
    out[b0 + tid] = s;
  }
}

extern "C" void kernel_launch(void* const* d_in, const int* in_sizes, int n_in,
                              void* d_out, int out_size, void* d_ws, size_t ws_size,
                              hipStream_t stream) {
  const float* x     = (const float*)d_in[0];
  const float* h0    = (const float*)d_in[1];
  const float* Wp    = (const float*)d_in[2];
  const float* bp    = (const float*)d_in[3];
  const float* Wih   = (const float*)d_in[4];
  const float* Whh   = (const float*)d_in[5];
  const float* bih   = (const float*)d_in[6];
  const float* bhh   = (const float*)d_in[7];
  const float* Whead = (const float*)d_in[8];
  const float* bhead = (const float*)d_in[9];
  float* out = (float*)d_out;
  unsigned short* ws = (unsigned short*)d_ws;

  cvt_w<<<(WS_TOT + 255) / 256, 256, 0, stream>>>(Wp, Wih, Whh, ws);
  gru_fused<<<B_N / 64, 512, 0, stream>>>(x, h0, ws, bp, bih, bhh, Whead, bhead, out);
}